// Round 8
// baseline (103.822 us; speedup 1.0000x reference)
//
#include <hip/hip_runtime.h>
#include <math.h>

#define LOG2PI_F 1.8378770664093453f
#define LOG2E_F  1.4426950408889634f
#define LN2_F    0.6931471805599453f
#define EXP_NEG1 0.36787944117144233f

#define ROWF   52      // floats per AC row: a[16] mu[16] C[16] P pad[3] (208B, 16B-aligned rows)
#define CHROWS 512     // j-rows per LDS chunk (106.5 KB -> 1 block/CU, 16 waves)
#define ITI    8       // i-rows per block
#define NT     1024    // threads per block

__device__ __forceinline__ float exp2_(float x) { return __builtin_amdgcn_exp2f(x); }
__device__ __forceinline__ float log2_(float x) { return __builtin_amdgcn_logf(x); }

// ws layout (floats): wsPart[256] @0, counter(int) @256, AC[B*52] @1024

// ---------------- K1: coefficient precompute (+ counter zero) ---------------
__global__ __launch_bounds__(256) void k_prep(const float* __restrict__ mu,
                                              const float* __restrict__ lv,
                                              const int* __restrict__ nds,
                                              float* __restrict__ ws, int B) {
    if (blockIdx.x == 0 && threadIdx.x == 0) *(int*)(ws + 256) = 0;
    float* AC = ws + 1024;
    int idx = blockIdx.x * 256 + threadIdx.x;
    int j = idx >> 4, d = idx & 15;
    float m = mu[idx], l = lv[idx];
    float a = -0.5f * LOG2E_F * __expf(-l);            // e = a*(v-m)^2 (log2 domain)
    float ec = -0.5f * LOG2E_F * (l + LOG2PI_F);       // log2 of norm const

    float Nf = (float)(*nds);
    float Mf = (float)(B - 1);
    float strat = (Nf - Mf) / (Nf * Mf);
    float w = (j == 0) ? (1.0f / Nf) : ((j == 1) ? strat : (1.0f / Mf));

    float* row = AC + (size_t)j * ROWF;
    row[d] = a;
    row[16 + d] = m;
    row[32 + d] = w * exp2_(ec);
    float es = ec;
    es += __shfl_xor(es, 1); es += __shfl_xor(es, 2);
    es += __shfl_xor(es, 4); es += __shfl_xor(es, 8);
    if (d == 0) row[48] = w * exp2_(es);
}

// ---------------- K2: everything else, one launch ---------------------------
// grid B/ITI = 256 blocks x 1024 thr. Block owns 8 i's, traverses all 2048 j
// in 4 LDS chunks. il = t&7, jgrp = t>>3 (128): row-in-chunk = jgrp + 128k.
__global__ __launch_bounds__(1024) void k_all(const float* __restrict__ ws_ac,
                                              const float* __restrict__ zg,
                                              const float* __restrict__ mu,
                                              const float* __restrict__ lv,
                                              const float4* __restrict__ x,
                                              const float4* __restrict__ r,
                                              const int* __restrict__ nds,
                                              float* __restrict__ wsPart,
                                              int* __restrict__ counter,
                                              float* __restrict__ out,
                                              int B, int n4,
                                              float invBF, float invB,
                                              int nblocks, int pb, int pil) {
    __shared__ float lds[CHROWS * ROWF];
    __shared__ float fin[16];
    __shared__ int lastFlag;

    const float* AC = ws_ac + 1024;
    const int t = threadIdx.x;
    const int bx = blockIdx.x;
    const int lane = t & 63, wv = t >> 6;
    const int il = t & 7;
    const int jgrp = t >> 3;
    const int i = bx * ITI + il;

    // ---- recon slice (coalesced, ~1 float4/thread) ----
    float rec_s = 0.0f;
    {
        int per = (n4 + nblocks - 1) / nblocks;
        int lo = bx * per, hi = min(lo + per, n4);
        for (int u = lo + t; u < hi; u += NT) {
            float4 a = x[u], b = r[u];
            rec_s += fabsf(a.x - b.x) + fabsf(a.y - b.y) + fabsf(a.z - b.z) + fabsf(a.w - b.w);
        }
    }
    // ---- lqzx - lprior elements for this block's 8 i's ----
    float gab = 0.0f;
    if (t < ITI * 16) {
        int iw = t >> 4, d = t & 15;
        int idx = (bx * ITI + iw) * 16 + d;
        float m = mu[idx], l = lv[idx], zz = zg[idx];
        float tt = zz - m;
        float ga = -0.5f * (fmaf(tt * tt, __expf(-l), l) + LOG2PI_F);
        float gb = -0.5f * (fmaf(zz * zz, EXP_NEG1, 1.0f) + LOG2PI_F);
        gab = ga - gb;
    }
    // ---- z row for my i ----
    float v[16];
    {
        const float4* zp = (const float4*)(zg + (size_t)i * 16);
        float4 a0 = zp[0], a1 = zp[1], a2 = zp[2], a3 = zp[3];
        v[0]=a0.x; v[1]=a0.y; v[2]=a0.z; v[3]=a0.w;
        v[4]=a1.x; v[5]=a1.y; v[6]=a1.z; v[7]=a1.w;
        v[8]=a2.x; v[9]=a2.y; v[10]=a2.z; v[11]=a2.w;
        v[12]=a3.x; v[13]=a3.y; v[14]=a3.z; v[15]=a3.w;
    }

    float sd[16];
    #pragma unroll
    for (int d = 0; d < 16; ++d) sd[d] = 0.0f;
    float stot = 0.0f;

    // ---- main loop: 4 chunks of 512 j-rows ----
    const int nch = B / CHROWS;
    for (int c = 0; c < nch; ++c) {
        __syncthreads();   // previous chunk's readers done
        {
            const float4* g = (const float4*)(AC + (size_t)c * CHROWS * ROWF);
            float4* s4 = (float4*)lds;
            for (int u = t; u < (CHROWS * ROWF) / 4; u += NT) s4[u] = g[u];
        }
        __syncthreads();
        #pragma unroll
        for (int k = 0; k < CHROWS / 128; ++k) {
            const float* rp = lds + (jgrp + 128 * k) * ROWF;
            float P = rp[48];
            float s2 = 0.0f;
            #pragma unroll
            for (int dq = 0; dq < 4; ++dq) {
                float4 aq = *(const float4*)(rp + dq * 4);
                float4 mq = *(const float4*)(rp + 16 + dq * 4);
                float4 cq = *(const float4*)(rp + 32 + dq * 4);
                const int d0 = dq * 4;
                float t0 = v[d0+0] - mq.x; float e0 = (aq.x * t0) * t0;
                float t1 = v[d0+1] - mq.y; float e1 = (aq.y * t1) * t1;
                float t2 = v[d0+2] - mq.z; float e2 = (aq.z * t2) * t2;
                float t3 = v[d0+3] - mq.w; float e3 = (aq.w * t3) * t3;
                s2 += (e0 + e1) + (e2 + e3);
                sd[d0+0] = fmaf(cq.x, exp2_(e0), sd[d0+0]);
                sd[d0+1] = fmaf(cq.y, exp2_(e1), sd[d0+1]);
                sd[d0+2] = fmaf(cq.z, exp2_(e2), sd[d0+2]);
                sd[d0+3] = fmaf(cq.w, exp2_(e3), sd[d0+3]);
            }
            stot = fmaf(P, exp2_(s2), stot);
        }
    }

    // ---- in-wave reduce over jgrp (lanes sharing il differ in bits 3..5) ----
    #pragma unroll
    for (int m = 8; m <= 32; m <<= 1) {
        stot += __shfl_xor(stot, m);
        #pragma unroll
        for (int d = 0; d < 16; ++d) sd[d] += __shfl_xor(sd[d], m);
    }
    __syncthreads();                       // done reading lds; reuse for red
    if (lane < 8) {
        float* wp = lds + (wv * 8 + lane) * 17;
        wp[0] = stot;
        #pragma unroll
        for (int d = 0; d < 16; ++d) wp[1 + d] = sd[d];
    }
    __syncthreads();

    // ---- per-(il,c) slot: cross-wave sum, patch, weighted log ----
    float contrib = 0.0f;
    if (t < ITI * 17) {                    // 136 threads; addr = w*136 + t (conflict-free)
        int il2 = t / 17, cc = t % 17;
        float S = 0.0f;
        #pragma unroll
        for (int w = 0; w < 16; ++w) S += lds[w * 136 + t];

        if (bx == pb && il2 == pil) {
            // W[B-2,0] = strat but prep folded 1/N: add delta using row 0
            const float* vv = zg + (size_t)(B - 2) * 16;
            float Nf = (float)(*nds);
            float Mf = (float)(B - 1);
            float dwN = (Nf - 2.0f * Mf) / Mf;      // (strat - 1/N) * N
            if (cc == 0) {
                float s2 = 0.0f;
                #pragma unroll
                for (int d = 0; d < 16; ++d) {
                    float tt = vv[d] - AC[16 + d];
                    s2 += (AC[d] * tt) * tt;
                }
                S += dwN * AC[48] * exp2_(s2);
            } else {
                int d = cc - 1;
                float tt = vv[d] - AC[16 + d];
                S += dwN * AC[32 + d] * exp2_((AC[d] * tt) * tt);
            }
        }
        contrib = ((cc == 0) ? 3.0f : -3.0f) * log2_(S) * LN2_F;
    }

    // ---- block grand total ----
    float phi = rec_s * invBF + (gab + contrib) * invB;
    #pragma unroll
    for (int off = 32; off > 0; off >>= 1) phi += __shfl_down(phi, off);
    if (lane == 0) fin[wv] = phi;
    __syncthreads();
    if (t == 0) {
        float s = 0.0f;
        #pragma unroll
        for (int w = 0; w < 16; ++w) s += fin[w];
        __hip_atomic_store(&wsPart[bx], s, __ATOMIC_RELEASE, __HIP_MEMORY_SCOPE_AGENT);
        int old = __hip_atomic_fetch_add(counter, 1, __ATOMIC_ACQ_REL, __HIP_MEMORY_SCOPE_AGENT);
        lastFlag = (old == nblocks - 1);
    }
    __syncthreads();

    if (lastFlag) {
        float q = 0.0f;
        if (t < nblocks)
            q = __hip_atomic_load(&wsPart[t], __ATOMIC_ACQUIRE, __HIP_MEMORY_SCOPE_AGENT);
        #pragma unroll
        for (int off = 32; off > 0; off >>= 1) q += __shfl_down(q, off);
        __syncthreads();                   // fin reuse safe
        if (lane == 0) fin[wv] = q;
        __syncthreads();
        if (t == 0) {
            float s = 0.0f;
            #pragma unroll
            for (int w = 0; w < 16; ++w) s += fin[w];
            out[0] = s;
        }
    }
}

extern "C" void kernel_launch(void* const* d_in, const int* in_sizes, int n_in,
                              void* d_out, int out_size, void* d_ws, size_t ws_size,
                              hipStream_t stream) {
    const float* x   = (const float*)d_in[0];
    const float* rec = (const float*)d_in[1];
    const float* mu  = (const float*)d_in[2];
    const float* lv  = (const float*)d_in[3];
    const float* z   = (const float*)d_in[4];
    const int*   nds = (const int*)d_in[5];

    const int BD = in_sizes[2];        // B * 16
    const int B  = BD / 16;            // 2048
    const int BF = in_sizes[0];        // B * F
    const int n4 = BF / 4;

    float* ws      = (float*)d_ws;
    float* wsPart  = ws;               // 256
    int*   counter = (int*)(ws + 256);
    const int nblocks = B / ITI;       // 256
    const int pb  = (B - 2) / ITI;     // block owning i = B-2
    const int pil = (B - 2) % ITI;

    k_prep<<<BD / 256, 256, 0, stream>>>(mu, lv, nds, ws, B);
    k_all<<<nblocks, NT, 0, stream>>>(ws, z, mu, lv,
                                      (const float4*)x, (const float4*)rec, nds,
                                      wsPart, counter, (float*)d_out,
                                      B, n4, 1.0f / (float)BF, 1.0f / (float)B,
                                      nblocks, pb, pil);
}